// Round 3
// baseline (470.476 us; speedup 1.0000x reference)
//
#include <hip/hip_runtime.h>
#include <hip/hip_fp16.h>

#define NNODES 50000
#define NEDGES 800000
#define NHEADS 4
#define HID 64
#define NEG_SLOPE 0.2f
#define NTOT (NEDGES + NNODES)

// ---------------- graph prep ----------------

__global__ void prep_init(int* deg, int* cursor) {
    int i = blockIdx.x * blockDim.x + threadIdx.x;
    if (i < NNODES) { deg[i] = 1; cursor[i] = 0; }  // deg starts at 1: self-loop
}

__global__ void hist_kernel(const int* __restrict__ dsts, int* __restrict__ deg) {
    int e = blockIdx.x * blockDim.x + threadIdx.x;
    if (e < NEDGES) atomicAdd(&deg[dsts[e]], 1);
}

// hierarchical exclusive scan: A (per-block), B (block totals), C (add offsets)
__global__ void scanA(const int* __restrict__ deg, int* __restrict__ rowstart,
                      int* __restrict__ partials) {
    int b = blockIdx.x, t = threadIdx.x, lane = t & 63, wid = t >> 6;
    int i = b * 256 + t;
    int v = (i < NNODES) ? deg[i] : 0;
    int incl = v;
#pragma unroll
    for (int off = 1; off < 64; off <<= 1) {
        int u = __shfl_up(incl, off, 64);
        if (lane >= off) incl += u;
    }
    __shared__ int ws[4];
    if (lane == 63) ws[wid] = incl;
    __syncthreads();
    int w0 = ws[0], w1 = ws[1], w2 = ws[2], w3 = ws[3];
    int woff = (wid > 0 ? w0 : 0) + (wid > 1 ? w1 : 0) + (wid > 2 ? w2 : 0);
    if (i < NNODES) rowstart[i] = woff + (incl - v);
    if (t == 0) partials[b] = w0 + w1 + w2 + w3;
}

__global__ void scanB(const int* __restrict__ partials, int* __restrict__ blockoff,
                      int* __restrict__ rowstart, int nb) {
    int t = threadIdx.x, lane = t & 63, wid = t >> 6;
    int v = (t < nb) ? partials[t] : 0;
    int incl = v;
#pragma unroll
    for (int off = 1; off < 64; off <<= 1) {
        int u = __shfl_up(incl, off, 64);
        if (lane >= off) incl += u;
    }
    __shared__ int ws[4];
    if (lane == 63) ws[wid] = incl;
    __syncthreads();
    int w0 = ws[0], w1 = ws[1], w2 = ws[2];
    int woff = (wid > 0 ? w0 : 0) + (wid > 1 ? w1 : 0) + (wid > 2 ? w2 : 0);
    if (t < nb) blockoff[t] = woff + (incl - v);
    if (t == 0) rowstart[NNODES] = NTOT;
}

__global__ void scanC(int* __restrict__ rowstart, const int* __restrict__ blockoff) {
    int b = blockIdx.x, t = threadIdx.x;
    int i = b * 256 + t;
    if (i < NNODES) rowstart[i] += blockoff[b];
}

__global__ void scatter_kernel(const int* __restrict__ srcs, const int* __restrict__ dsts,
                               const int* __restrict__ rowstart, int* __restrict__ cursor,
                               int* __restrict__ srclist) {
    int e = blockIdx.x * blockDim.x + threadIdx.x;
    if (e < NEDGES) {
        int s = srcs[e], d = dsts[e];
        int pos = atomicAdd(&cursor[d], 1);
        srclist[rowstart[d] + pos] = s;
    } else if (e < NTOT) {
        int d = e - NEDGES;
        int pos = atomicAdd(&cursor[d], 1);
        srclist[rowstart[d] + pos] = d;  // self-loop
    }
}

__global__ void w2_convert(const float* __restrict__ W2, __half* __restrict__ W2h) {
    int i = blockIdx.x * blockDim.x + threadIdx.x;
    if (i < 256 * 64) W2h[i] = __float2half(W2[i]);
}

// ---------------- layer 1 ----------------

// one block (256 thr) per node: h1 = x @ W1, stored fp16 in XCD-sharded layout
// h1s[shard][node][32 halves], shard = head*2 + (dim-half). att dots per head.
__global__ void layer1_proj(const float* __restrict__ x, const float* __restrict__ W1,
                            const float* __restrict__ att_src, const float* __restrict__ att_dst,
                            __half* __restrict__ h1s, float* __restrict__ asrc_h,
                            float* __restrict__ adst_h) {
    int nid = blockIdx.x;
    int t = threadIdx.x;
    __shared__ float xr[16];
    if (t < 15) xr[t] = x[nid * 15 + t];
    __syncthreads();
    float acc = 0.f;
#pragma unroll
    for (int k = 0; k < 15; ++k) acc += xr[k] * W1[k * 256 + t];
    int h = t >> 6, hd = t & 63;
    int shard = h * 2 + (hd >> 5);
    h1s[((size_t)shard * NNODES + nid) * 32 + (hd & 31)] = __float2half(acc);
    float ps = acc * att_src[h * 64 + hd];
    float pd = acc * att_dst[h * 64 + hd];
#pragma unroll
    for (int off = 32; off; off >>= 1) {
        ps += __shfl_down(ps, off, 64);
        pd += __shfl_down(pd, off, 64);
    }
    if (hd == 0) { asrc_h[h * NNODES + nid] = ps; adst_h[h * NNODES + nid] = pd; }
}

// 8 waves/block, one (node, shard) per wave; shard = blockIdx&7 -> XCD via round-robin.
// Per-XCD L2 working set: one 3.2 MB h1 shard + 200 KB asrc table -> L2-resident gathers.
// Single-pass unnormalized softmax (e is O(+-3): exp cannot overflow; alpha=w/z exact).
__global__ void layer1_aggr(const __half2* __restrict__ h1s, const int* __restrict__ rowstart,
                            const int* __restrict__ srclist,
                            const float* __restrict__ asrc_h, const float* __restrict__ adst_h,
                            const float* __restrict__ b1, __half* __restrict__ out1) {
    int g = blockIdx.x;
    int shard = g & 7, h = shard >> 1, half = shard & 1;
    int wid = threadIdx.x >> 6, lane = threadIdx.x & 63;
    int nid = (g >> 3) * 8 + wid;
    int q = lane >> 4, d = lane & 15;   // q: edge slot (4), d: half2 index (16 per shard row)
    int beg = rowstart[nid], end = rowstart[nid + 1];
    float ad = adst_h[h * NNODES + nid];
    const __half2* hrow = h1s + (size_t)shard * NNODES * 16;
    const float* as = asrc_h + (size_t)h * NNODES;

    float zl = 0.f, ax = 0.f, ay = 0.f;
    for (int i0 = beg; i0 < end; i0 += 64) {
        int i = i0 + lane;
        int s = 0; float w = 0.f;
        if (i < end) {
            s = srclist[i];
            float e = as[s] + ad;
            e = fmaxf(e, NEG_SLOPE * e);  // LeakyReLU
            w = __expf(e);
        }
        zl += w;
        int cnt = end - i0; if (cnt > 64) cnt = 64;
        for (int j = 0; j < cnt; j += 8) {       // 8 edges/iter: 2 indep loads/lane for MLP
            int j1 = j + q, j2 = j + 4 + q;      // >= cnt is harmless: w=0, s=0
            float w1 = __shfl(w, j1, 64); int s1 = __shfl(s, j1, 64);
            float w2 = __shfl(w, j2, 64); int s2 = __shfl(s, j2, 64);
            float2 v1 = __half22float2(hrow[s1 * 16 + d]);
            float2 v2 = __half22float2(hrow[s2 * 16 + d]);
            ax += w1 * v1.x + w2 * v2.x;
            ay += w1 * v1.y + w2 * v2.y;
        }
    }
#pragma unroll
    for (int off = 32; off; off >>= 1) zl += __shfl_xor(zl, off, 64);
    ax += __shfl_xor(ax, 16, 64); ax += __shfl_xor(ax, 32, 64);
    ay += __shfl_xor(ay, 16, 64); ay += __shfl_xor(ay, 32, 64);
    if (q == 0) {
        float r = 1.f / zl;
        float2 bo = ((const float2*)b1)[h * 32 + half * 16 + d];
        float o0 = ax * r + bo.x;
        float o1 = ay * r + bo.y;
        o0 = o0 > 0.f ? o0 : __expf(o0) - 1.f;  // ELU
        o1 = o1 > 0.f ? o1 : __expf(o1) - 1.f;
        ((__half2*)out1)[nid * 128 + h * 32 + half * 16 + d] = __floats2half2_rn(o0, o1);
    }
}

// ---------------- layer 2 ----------------

// one wave per node: h2 = elu_out @ W2 (256->64, fp16 weights), h2 stored in 2 shards;
// attention dots (heads=1)
__global__ void layer2_proj(const __half* __restrict__ out1, const __half* __restrict__ W2h,
                            const float* __restrict__ att_src2, const float* __restrict__ att_dst2,
                            __half* __restrict__ h2s, float* __restrict__ as2,
                            float* __restrict__ ad2) {
    int nid = blockIdx.x;
    int t = threadIdx.x;  // 64
    int sub = t >> 5, d = t & 31;
    __shared__ float row[256];
    const __half2* r = (const __half2*)(out1 + nid * 256);
    for (int k = t; k < 128; k += 64) {
        float2 v = __half22float2(r[k]);
        row[2 * k] = v.x; row[2 * k + 1] = v.y;
    }
    __syncthreads();
    float ax = 0.f, ay = 0.f;
    const __half2* wp = (const __half2*)W2h;  // [256][64] halves -> half2 index k*32+d
#pragma unroll 8
    for (int kk = 0; kk < 128; ++kk) {
        int k = sub * 128 + kk;
        float2 wv = __half22float2(wp[k * 32 + d]);
        float rv = row[k];
        ax += rv * wv.x;
        ay += rv * wv.y;
    }
    ax += __shfl_xor(ax, 32, 64);
    ay += __shfl_xor(ay, 32, 64);
    // both halves hold full sums for dims (2d, 2d+1); shard = d>>4 (dims 0..31 / 32..63)
    if (sub == 0)
        ((__half2*)h2s)[((size_t)(d >> 4) * NNODES + nid) * 16 + (d & 15)] = __floats2half2_rn(ax, ay);
    float2 asv = ((const float2*)att_src2)[d];
    float2 adv = ((const float2*)att_dst2)[d];
    float ps = ax * asv.x + ay * asv.y;
    float pd = ax * adv.x + ay * adv.y;
#pragma unroll
    for (int off = 16; off; off >>= 1) {
        ps += __shfl_xor(ps, off, 64);
        pd += __shfl_xor(pd, off, 64);
    }
    if (t == 0) { as2[nid] = ps; ad2[nid] = pd; }
}

// 8 waves/block, one (node, shard) per wave; shard = blockIdx&1 -> even/odd XCDs.
// Per-XCD L2 working set: 3.2 MB h2 shard + 200 KB as2 -> L2-resident.
__global__ void layer2_aggr(const __half2* __restrict__ h2s, const int* __restrict__ rowstart,
                            const int* __restrict__ srclist,
                            const float* __restrict__ as2, const float* __restrict__ ad2,
                            const float* __restrict__ b2, float* __restrict__ out2) {
    int g = blockIdx.x;
    int shard = g & 1;
    int wid = threadIdx.x >> 6, lane = threadIdx.x & 63;
    int nid = (g >> 1) * 8 + wid;
    int q = lane >> 4, d = lane & 15;
    int beg = rowstart[nid], end = rowstart[nid + 1];
    float ad = ad2[nid];
    const __half2* hrow = h2s + (size_t)shard * NNODES * 16;

    float zl = 0.f, ax = 0.f, ay = 0.f;
    for (int i0 = beg; i0 < end; i0 += 64) {
        int i = i0 + lane;
        int s = 0; float w = 0.f;
        if (i < end) {
            s = srclist[i];
            float e = as2[s] + ad;
            e = fmaxf(e, NEG_SLOPE * e);
            w = __expf(e);
        }
        zl += w;
        int cnt = end - i0; if (cnt > 64) cnt = 64;
        for (int j = 0; j < cnt; j += 8) {
            int j1 = j + q, j2 = j + 4 + q;
            float w1 = __shfl(w, j1, 64); int s1 = __shfl(s, j1, 64);
            float w2 = __shfl(w, j2, 64); int s2 = __shfl(s, j2, 64);
            float2 v1 = __half22float2(hrow[s1 * 16 + d]);
            float2 v2 = __half22float2(hrow[s2 * 16 + d]);
            ax += w1 * v1.x + w2 * v2.x;
            ay += w1 * v1.y + w2 * v2.y;
        }
    }
#pragma unroll
    for (int off = 32; off; off >>= 1) zl += __shfl_xor(zl, off, 64);
    ax += __shfl_xor(ax, 16, 64); ax += __shfl_xor(ax, 32, 64);
    ay += __shfl_xor(ay, 16, 64); ay += __shfl_xor(ay, 32, 64);
    if (q == 0) {
        float r = 1.f / zl;
        float2 bo = ((const float2*)b2)[shard * 16 + d];
        ((float2*)out2)[nid * 32 + shard * 16 + d] =
            make_float2(ax * r + bo.x, ay * r + bo.y);
    }
}

// ---------------- final mean over nodes ----------------

__global__ void reduce_kernel(const float* __restrict__ out2, float* __restrict__ dout) {
    int t = threadIdx.x;
    int col = t & 63, sub = t >> 6;
    float acc = 0.f;
    for (int r = blockIdx.x * 4 + sub; r < NNODES; r += 256 * 4)
        acc += out2[r * 64 + col];
    __shared__ float sh[256];
    sh[t] = acc;
    __syncthreads();
    if (t < 64) {
        float v = sh[t] + sh[t + 64] + sh[t + 128] + sh[t + 192];
        atomicAdd(&dout[t], v * (1.0f / NNODES));
    }
}

// ---------------- launch ----------------

extern "C" void kernel_launch(void* const* d_in, const int* in_sizes, int n_in,
                              void* d_out, int out_size, void* d_ws, size_t ws_size,
                              hipStream_t stream) {
    const float* x        = (const float*)d_in[0];
    const int*   ei       = (const int*)d_in[1];   // [2, E] -> src row then dst row
    const float* W1       = (const float*)d_in[2];
    const float* att_src1 = (const float*)d_in[3];
    const float* att_dst1 = (const float*)d_in[4];
    const float* b1       = (const float*)d_in[5];
    const float* W2       = (const float*)d_in[6];
    const float* att_src2 = (const float*)d_in[7];
    const float* att_dst2 = (const float*)d_in[8];
    const float* b2       = (const float*)d_in[9];
    float* out = (float*)d_out;

    char* ws = (char*)d_ws;
    size_t off = 0;
    auto take = [&](size_t bytes) -> char* {
        char* p = ws + off;
        off = (off + bytes + 255) & ~(size_t)255;
        return p;
    };
    int*    deg      = (int*)take(NNODES * sizeof(int));
    int*    rowstart = (int*)take((NNODES + 1) * sizeof(int));
    int*    cursor   = (int*)take(NNODES * sizeof(int));
    int*    partials = (int*)take(256 * sizeof(int));
    int*    blockoff = (int*)take(256 * sizeof(int));
    int*    srclist  = (int*)take((size_t)NTOT * sizeof(int));
    float*  asrc_h   = (float*)take((size_t)NNODES * NHEADS * sizeof(float));
    float*  adst_h   = (float*)take((size_t)NNODES * NHEADS * sizeof(float));
    __half* h1s      = (__half*)take((size_t)NNODES * 256 * sizeof(__half));
    __half* out1     = (__half*)take((size_t)NNODES * 256 * sizeof(__half));
    __half* h2s      = (__half*)take((size_t)NNODES * 64 * sizeof(__half));
    float*  as2      = (float*)take((size_t)NNODES * sizeof(float));
    float*  ad2      = (float*)take((size_t)NNODES * sizeof(float));
    float*  out2     = (float*)take((size_t)NNODES * 64 * sizeof(float));
    __half* W2h      = (__half*)take(256 * 64 * sizeof(__half));

    const int* srcs = ei;
    const int* dsts = ei + NEDGES;
    const int NB = (NNODES + 255) / 256;  // 196

    prep_init<<<NB, 256, 0, stream>>>(deg, cursor);
    hist_kernel<<<(NEDGES + 255) / 256, 256, 0, stream>>>(dsts, deg);
    scanA<<<NB, 256, 0, stream>>>(deg, rowstart, partials);
    scanB<<<1, 256, 0, stream>>>(partials, blockoff, rowstart, NB);
    scanC<<<NB, 256, 0, stream>>>(rowstart, blockoff);
    scatter_kernel<<<(NTOT + 255) / 256, 256, 0, stream>>>(srcs, dsts, rowstart, cursor, srclist);
    w2_convert<<<64, 256, 0, stream>>>(W2, W2h);

    layer1_proj<<<NNODES, 256, 0, stream>>>(x, W1, att_src1, att_dst1, h1s, asrc_h, adst_h);
    // 8 shards x (50000/8 per-block groups) ; 512 threads = 8 waves = 8 nodes, same shard
    layer1_aggr<<<(NNODES / 8) * 8, 512, 0, stream>>>((const __half2*)h1s, rowstart, srclist,
                                                      asrc_h, adst_h, b1, out1);

    layer2_proj<<<NNODES, 64, 0, stream>>>(out1, W2h, att_src2, att_dst2, h2s, as2, ad2);
    layer2_aggr<<<(NNODES / 8) * 2, 512, 0, stream>>>((const __half2*)h2s, rowstart, srclist,
                                                      as2, ad2, b2, out2);

    hipMemsetAsync(d_out, 0, 64 * sizeof(float), stream);
    reduce_kernel<<<256, 256, 0, stream>>>(out2, out);
}